// Round 8
// baseline (177.413 us; speedup 1.0000x reference)
//
#include <hip/hip_runtime.h>

#define H       128
#define NNODES  50000
#define NEDGES  640000
#define NTYPES  16
#define EDIM    8
#define BCAP    64        // fixed bucket capacity (max degree; lambda=12.8, P(>=64)~1e-25)
#define PSTRIDE 132       // projL row stride in floats (16B-aligned, 4-bank shift/row)

// prep_kernel block partition: bucket | xb | proj | pack
#define BKT_BLOCKS  2500                  // 640000 / 256
#define XB_BLOCKS   3125                  // 6.4M elems / 8 / 256
#define PROJ_BLOCKS 8
#define PACK_BLOCKS 16
#define PREP_BLOCKS (BKT_BLOCKS + XB_BLOCKS + PROJ_BLOCKS + PACK_BLOCKS)

typedef __attribute__((ext_vector_type(8))) __bf16 bf16x8;
typedef __attribute__((ext_vector_type(4))) float  f32x4;

// round-to-nearest-even float -> bf16 bits
__device__ __forceinline__ unsigned short f2bf(float f) {
    unsigned int u = __float_as_uint(f);
    u += 0x7fffu + ((u >> 16) & 1u);
    return (unsigned short)(u >> 16);
}

// acc += relu(expand(g) + q), 8 feats (g = 8 bf16 in uint4, q = qa|qb)
__device__ __forceinline__ void acc8(uint4 g, float4 qa, float4 qb,
                                     float4& A, float4& B) {
    A.x += fmaxf(__uint_as_float(g.x << 16)         + qa.x, 0.f);
    A.y += fmaxf(__uint_as_float(g.x & 0xffff0000u) + qa.y, 0.f);
    A.z += fmaxf(__uint_as_float(g.y << 16)         + qa.z, 0.f);
    A.w += fmaxf(__uint_as_float(g.y & 0xffff0000u) + qa.w, 0.f);
    B.x += fmaxf(__uint_as_float(g.z << 16)         + qb.x, 0.f);
    B.y += fmaxf(__uint_as_float(g.z & 0xffff0000u) + qb.y, 0.f);
    B.z += fmaxf(__uint_as_float(g.w << 16)         + qb.z, 0.f);
    B.w += fmaxf(__uint_as_float(g.w & 0xffff0000u) + qb.w, 0.f);
}

// ---------------------------------------------------------------------------
// fused prep; all four parts independent. cursor must be zeroed beforehand.
//   [0, 2500)        : bucket  edges -> packed[dst*64 + pos], cursor = degree
//   [2500, 5625)     : x (fp32) -> xb (bf16)
//   [5625, 5633)     : proj = emb @ We + be   (16 x 128, packed fp32)
//   [5633, 5649)     : pack W1/W2 into MFMA B-frag order (bf16)
// ---------------------------------------------------------------------------
__global__ __launch_bounds__(256) void prep_kernel(
        const float* __restrict__ x, unsigned short* __restrict__ xb,
        const int* __restrict__ edge_index, const int* __restrict__ edge_attr,
        int* __restrict__ cursor, unsigned int* __restrict__ packed,
        const float* __restrict__ emb, const float* __restrict__ We,
        const float* __restrict__ be, float* __restrict__ proj,
        const float* __restrict__ W1, const float* __restrict__ W2,
        unsigned short* __restrict__ w1p, unsigned short* __restrict__ w2p) {
    const int b = blockIdx.x;
    const int t = threadIdx.x;

    if (b < BKT_BLOCKS) {
        // bucket: one edge per thread
        int e = b * 256 + t;                 // 2500*256 == 640000 exactly
        int src = edge_index[e];
        int dst = edge_index[NEDGES + e];
        int a0 = edge_attr[e * 3 + 0];
        int a1 = edge_attr[e * 3 + 1];
        int a2 = edge_attr[e * 3 + 2];
        unsigned int h = (unsigned int)(a0 + 3 * a1 + 7 * a2) & (NTYPES - 1);
        int pos = atomicAdd(&cursor[dst], 1);
        if (pos < BCAP)
            packed[((unsigned)dst << 6) + pos] = (unsigned int)src | (h << 16);
    } else if (b < BKT_BLOCKS + XB_BLOCKS) {
        // x (fp32) -> xb (bf16), 8 elems/thread
        int i = ((b - BKT_BLOCKS) * 256 + t) * 8;
        float4 a = *(const float4*)(x + i);
        float4 c = *(const float4*)(x + i + 4);
        int4 o;
        o.x = (int)((unsigned int)f2bf(a.x) | ((unsigned int)f2bf(a.y) << 16));
        o.y = (int)((unsigned int)f2bf(a.z) | ((unsigned int)f2bf(a.w) << 16));
        o.z = (int)((unsigned int)f2bf(c.x) | ((unsigned int)f2bf(c.y) << 16));
        o.w = (int)((unsigned int)f2bf(c.z) | ((unsigned int)f2bf(c.w) << 16));
        *(int4*)(xb + i) = o;
    } else if (b < BKT_BLOCKS + XB_BLOCKS + PROJ_BLOCKS) {
        // proj[t][f] = be[f] + sum_d emb[t][d]*We[d][f]
        int id = (b - BKT_BLOCKS - XB_BLOCKS) * 256 + t;   // 0..2047
        int ty = id >> 7;
        int f  = id & (H - 1);
        float acc = be[f];
#pragma unroll
        for (int d = 0; d < EDIM; ++d)
            acc += emb[ty * EDIM + d] * We[d * H + f];
        proj[id] = acc;
    } else {
        // pack W1/W2 into MFMA B-fragment order (bf16), verified R4
        int id = (b - BKT_BLOCKS - XB_BLOCKS - PROJ_BLOCKS) * 256 + t; // 0..4095
        const float* W = (id < 2048) ? W1 : W2;
        unsigned short* P = (id < 2048) ? w1p : w2p;
        int q = id & 2047;
        int lane = q & 63;
        int kc = (q >> 6) & 3;
        int c  = q >> 8;
        int n = c * 16 + (lane & 15);
        int kbase = kc * 32 + (lane >> 4) * 8;
#pragma unroll
        for (int j = 0; j < 8; ++j)
            P[q * 8 + j] = f2bf(W[(kbase + j) * H + n]);
    }
}

// ---------------------------------------------------------------------------
// fused: block = 16 nodes = one MFMA tile, 4 waves.
// Aggregation: each 16-lane group owns ONE node; lane covers 8 features
// (dwordx4 gather), so per edge: 1 global_load_dwordx4 + 2 ds_read_b128.
// Then the 4 waves split the 8 col-chunks of each GEMM (2 each).
// ---------------------------------------------------------------------------
__global__ __launch_bounds__(256) void gine_fused_kernel(
        const unsigned short* __restrict__ xb,
        const int* __restrict__ deg,
        const unsigned int* __restrict__ packed,
        const float* __restrict__ proj,
        const float* __restrict__ epsp,
        const unsigned short* __restrict__ w1p,
        const unsigned short* __restrict__ w2p,
        const float* __restrict__ b1,
        const float* __restrict__ b2,
        float* __restrict__ out) {
    __shared__ float projL[NTYPES * PSTRIDE];    // 8.25 KB
    __shared__ unsigned short Tz[16 * 136];      // 4.25 KB
    __shared__ unsigned short Th[16 * 136];      // 4.25 KB
    const int t = threadIdx.x;
    // stage proj [16][128] -> projL stride 132
#pragma unroll
    for (int i = 0; i < 2; ++i) {
        int idx = t + i * 256;          // float4 index 0..511
        int r = idx >> 5, c4 = idx & 31;
        *(float4*)(projL + r * PSTRIDE + c4 * 4) = ((const float4*)proj)[idx];
    }
    __syncthreads();

    const int w = t >> 6, lane = t & 63;
    const int grp = lane >> 4, sub = lane & 15;
    const int nodeBase = blockIdx.x * 16;
    const float scale = 1.0f + *epsp;

    // ---- aggregation: group grp of wave w owns node w*4+grp ----
    const int row  = w * 4 + grp;
    const int node = nodeBase + row;
    const int s = node << 6;
    int d = deg[node]; if (d > BCAP) d = BCAP;
    const int e = s + d;
    const int sub8 = sub * 8;

    float4 A = {0.f, 0.f, 0.f, 0.f}, B = {0.f, 0.f, 0.f, 0.f};
    int j = s;
    for (; j + 1 < e; j += 2) {
        unsigned int p0 = packed[j];
        unsigned int p1 = packed[j + 1];
        uint4 g0 = *(const uint4*)(xb + ((p0 & 0xffffu) << 7) + sub8);
        uint4 g1 = *(const uint4*)(xb + ((p1 & 0xffffu) << 7) + sub8);
        const float* q0 = projL + (p0 >> 16) * PSTRIDE + sub8;
        const float* q1 = projL + (p1 >> 16) * PSTRIDE + sub8;
        float4 qa0 = *(const float4*)q0, qb0 = *(const float4*)(q0 + 4);
        float4 qa1 = *(const float4*)q1, qb1 = *(const float4*)(q1 + 4);
        acc8(g0, qa0, qb0, A, B);
        acc8(g1, qa1, qb1, A, B);
    }
    if (j < e) {
        unsigned int p0 = packed[j];
        uint4 g0 = *(const uint4*)(xb + ((p0 & 0xffffu) << 7) + sub8);
        const float* q0 = projL + (p0 >> 16) * PSTRIDE + sub8;
        acc8(g0, *(const float4*)q0, *(const float4*)(q0 + 4), A, B);
    }

    // self term + bf16 pack -> Tz
    {
        uint4 go = *(const uint4*)(xb + ((unsigned)node << 7) + sub8);
        float z0 = scale * __uint_as_float(go.x << 16)         + A.x;
        float z1 = scale * __uint_as_float(go.x & 0xffff0000u) + A.y;
        float z2 = scale * __uint_as_float(go.y << 16)         + A.z;
        float z3 = scale * __uint_as_float(go.y & 0xffff0000u) + A.w;
        float z4 = scale * __uint_as_float(go.z << 16)         + B.x;
        float z5 = scale * __uint_as_float(go.z & 0xffff0000u) + B.y;
        float z6 = scale * __uint_as_float(go.w << 16)         + B.z;
        float z7 = scale * __uint_as_float(go.w & 0xffff0000u) + B.w;
        uint4 o;
        o.x = (unsigned int)f2bf(z0) | ((unsigned int)f2bf(z1) << 16);
        o.y = (unsigned int)f2bf(z2) | ((unsigned int)f2bf(z3) << 16);
        o.z = (unsigned int)f2bf(z4) | ((unsigned int)f2bf(z5) << 16);
        o.w = (unsigned int)f2bf(z6) | ((unsigned int)f2bf(z7) << 16);
        *(uint4*)(Tz + row * 136 + sub8) = o;
    }
    __syncthreads();

    // ---- MFMA MLP: wave w owns col-chunks {w, w+4} of each GEMM ----
    const int m = lane & 15, quad = lane >> 4;

    bf16x8 a[4];
#pragma unroll
    for (int kc = 0; kc < 4; ++kc)
        a[kc] = *(const bf16x8*)(Tz + m * 136 + kc * 32 + quad * 8);

    const bf16x8* w1f = (const bf16x8*)w1p;
#pragma unroll
    for (int cc = 0; cc < 2; ++cc) {
        const int c = w + cc * 4;
        f32x4 acc = {0.f, 0.f, 0.f, 0.f};
#pragma unroll
        for (int kc = 0; kc < 4; ++kc)
            acc = __builtin_amdgcn_mfma_f32_16x16x32_bf16(
                      a[kc], w1f[(c * 4 + kc) * 64 + lane], acc, 0, 0, 0);
        const int col = c * 16 + m;
        const float bias = b1[col];
#pragma unroll
        for (int r = 0; r < 4; ++r)
            Th[(quad * 4 + r) * 136 + col] = f2bf(fmaxf(acc[r] + bias, 0.0f));
    }
    __syncthreads();

    bf16x8 ha[4];
#pragma unroll
    for (int kc = 0; kc < 4; ++kc)
        ha[kc] = *(const bf16x8*)(Th + m * 136 + kc * 32 + quad * 8);

    const bf16x8* w2f = (const bf16x8*)w2p;
#pragma unroll
    for (int cc = 0; cc < 2; ++cc) {
        const int c = w + cc * 4;
        f32x4 acc = {0.f, 0.f, 0.f, 0.f};
#pragma unroll
        for (int kc = 0; kc < 4; ++kc)
            acc = __builtin_amdgcn_mfma_f32_16x16x32_bf16(
                      ha[kc], w2f[(c * 4 + kc) * 64 + lane], acc, 0, 0, 0);
        const int col = c * 16 + m;
        const float bias = b2[col];
#pragma unroll
        for (int r = 0; r < 4; ++r)
            out[(size_t)(nodeBase + quad * 4 + r) * H + col] = acc[r] + bias;
    }
}

// ---------------------------------------------------------------------------
extern "C" void kernel_launch(void* const* d_in, const int* in_sizes, int n_in,
                              void* d_out, int out_size, void* d_ws, size_t ws_size,
                              hipStream_t stream) {
    const float* x          = (const float*)d_in[0];
    const int*   edge_index = (const int*)  d_in[1];
    const int*   edge_attr  = (const int*)  d_in[2];
    const float* emb        = (const float*)d_in[3];
    const float* We         = (const float*)d_in[4];
    const float* be         = (const float*)d_in[5];
    const float* W1         = (const float*)d_in[6];
    const float* b1         = (const float*)d_in[7];
    const float* W2         = (const float*)d_in[8];
    const float* b2         = (const float*)d_in[9];
    const float* eps        = (const float*)d_in[10];
    float* out = (float*)d_out;

    char* ws = (char*)d_ws;
    size_t off = 0;
    float* proj    = (float*)(ws + off); off += (size_t)NTYPES * H * 4;                  // 8 KB
    int*   cursor  = (int*)  (ws + off); off += (size_t)NNODES * 4;                      // 200 KB
    unsigned int*   packed = (unsigned int*)(ws + off);   off += (size_t)NNODES * BCAP * 4; // 12.8 MB
    unsigned short* xb     = (unsigned short*)(ws + off); off += (size_t)NNODES * H * 2;    // 12.8 MB
    unsigned short* w1p    = (unsigned short*)(ws + off); off += 2048 * 8 * 2;           // 32 KB
    unsigned short* w2p    = (unsigned short*)(ws + off); off += 2048 * 8 * 2;           // 32 KB

    hipMemsetAsync(cursor, 0, (size_t)NNODES * sizeof(int), stream);

    prep_kernel<<<PREP_BLOCKS, 256, 0, stream>>>(
        x, xb, edge_index, edge_attr, cursor, packed,
        emb, We, be, proj, W1, W2, w1p, w2p);

    gine_fused_kernel<<<NNODES / 16, 256, 0, stream>>>(
        xb, cursor, packed, proj, eps, w1p, w2p, b1, b2, out);
}

// Round 9
// 172.992 us; speedup vs baseline: 1.0256x; 1.0256x over previous
//
#include <hip/hip_runtime.h>

#define H       128
#define NNODES  50000
#define NEDGES  640000
#define NTYPES  16
#define EDIM    8
#define BCAP    32        // fixed bucket capacity (lambda=12.8, P(deg>=33)~5e-22 over 50k)
#define TSTR    136       // LDS row stride in halves (16B-aligned, 4-bank shift/row)

// prep_kernel block partition: bucket | xh | proj | pack
#define BKT_BLOCKS  2500                  // 640000 / 256
#define XH_BLOCKS   3125                  // 6.4M elems / 8 / 256
#define PROJ_BLOCKS 8
#define PACK_BLOCKS 16
#define PREP_BLOCKS (BKT_BLOCKS + XH_BLOCKS + PROJ_BLOCKS + PACK_BLOCKS)

typedef _Float16 h8 __attribute__((ext_vector_type(8)));
typedef float    f32x4 __attribute__((ext_vector_type(4)));

// ---------------------------------------------------------------------------
// fused prep; all four parts independent. cursor must be zeroed beforehand.
//   [0, 2500)    : bucket edges -> packed[dst*32 + pos], cursor = degree
//   [2500, 5625) : x (fp32) -> xh (fp16)
//   [5625, 5633) : projh = fp16(emb @ We + be)   (16 x 128)
//   [5633, 5649) : pack W1/W2 into MFMA B-frag order (fp16)
// ---------------------------------------------------------------------------
__global__ __launch_bounds__(256) void prep_kernel(
        const float* __restrict__ x, _Float16* __restrict__ xh,
        const int* __restrict__ edge_index, const int* __restrict__ edge_attr,
        int* __restrict__ cursor, unsigned int* __restrict__ packed,
        const float* __restrict__ emb, const float* __restrict__ We,
        const float* __restrict__ be, _Float16* __restrict__ projh,
        const float* __restrict__ W1, const float* __restrict__ W2,
        _Float16* __restrict__ w1p, _Float16* __restrict__ w2p) {
    const int b = blockIdx.x;
    const int t = threadIdx.x;

    if (b < BKT_BLOCKS) {
        // bucket: one edge per thread
        int e = b * 256 + t;                 // 2500*256 == 640000 exactly
        int src = edge_index[e];
        int dst = edge_index[NEDGES + e];
        int a0 = edge_attr[e * 3 + 0];
        int a1 = edge_attr[e * 3 + 1];
        int a2 = edge_attr[e * 3 + 2];
        unsigned int h = (unsigned int)(a0 + 3 * a1 + 7 * a2) & (NTYPES - 1);
        int pos = atomicAdd(&cursor[dst], 1);
        if (pos < BCAP)
            packed[((unsigned)dst << 5) + pos] = (unsigned int)src | (h << 16);
    } else if (b < BKT_BLOCKS + XH_BLOCKS) {
        // x (fp32) -> xh (fp16), 8 elems/thread
        int i = ((b - BKT_BLOCKS) * 256 + t) * 8;
        float4 a = *(const float4*)(x + i);
        float4 c = *(const float4*)(x + i + 4);
        h8 o;
        o[0] = (_Float16)a.x; o[1] = (_Float16)a.y;
        o[2] = (_Float16)a.z; o[3] = (_Float16)a.w;
        o[4] = (_Float16)c.x; o[5] = (_Float16)c.y;
        o[6] = (_Float16)c.z; o[7] = (_Float16)c.w;
        *(h8*)(xh + i) = o;
    } else if (b < BKT_BLOCKS + XH_BLOCKS + PROJ_BLOCKS) {
        // projh[t][f] = fp16(be[f] + sum_d emb[t][d]*We[d][f])
        int id = (b - BKT_BLOCKS - XH_BLOCKS) * 256 + t;   // 0..2047
        int ty = id >> 7;
        int f  = id & (H - 1);
        float acc = be[f];
#pragma unroll
        for (int d = 0; d < EDIM; ++d)
            acc += emb[ty * EDIM + d] * We[d * H + f];
        projh[id] = (_Float16)acc;
    } else {
        // pack W1/W2 into MFMA B-fragment order (fp16); layout verified R4
        int id = (b - BKT_BLOCKS - XH_BLOCKS - PROJ_BLOCKS) * 256 + t; // 0..4095
        const float* W = (id < 2048) ? W1 : W2;
        _Float16* P = (id < 2048) ? w1p : w2p;
        int q = id & 2047;
        int lane = q & 63;
        int kc = (q >> 6) & 3;
        int c  = q >> 8;
        int n = c * 16 + (lane & 15);
        int kbase = kc * 32 + (lane >> 4) * 8;
#pragma unroll
        for (int j = 0; j < 8; ++j)
            P[q * 8 + j] = (_Float16)W[(kbase + j) * H + n];
    }
}

// ---------------------------------------------------------------------------
// fused: block = 16 nodes = one MFMA tile, 4 waves.
// Aggregation: each 16-lane group owns ONE node; lane covers 8 features.
// Per edge: 1 global_load_dwordx4 (xh) + 1 ds_read_b128 (projh) + 12 pk-f16
// ops (add/max/acc). Then the 4 waves split the 8 col-chunks of each GEMM.
// ---------------------------------------------------------------------------
__global__ __launch_bounds__(256) void gine_fused_kernel(
        const _Float16* __restrict__ xh,
        const int* __restrict__ deg,
        const unsigned int* __restrict__ packed,
        const _Float16* __restrict__ projh,
        const float* __restrict__ epsp,
        const _Float16* __restrict__ w1p,
        const _Float16* __restrict__ w2p,
        const float* __restrict__ b1,
        const float* __restrict__ b2,
        float* __restrict__ out) {
    __shared__ _Float16 projL[NTYPES * TSTR];    // 4.25 KB
    __shared__ _Float16 Tz[16 * TSTR];           // 4.25 KB
    __shared__ _Float16 Th[16 * TSTR];           // 4.25 KB
    const int t = threadIdx.x;
    // stage projh [16][128] -> projL stride 136 (one 16B chunk per thread)
    {
        int r = t >> 4, cc = (t & 15) * 8;
        *(h8*)(projL + r * TSTR + cc) = *(const h8*)(projh + r * H + cc);
    }
    __syncthreads();

    const int w = t >> 6, lane = t & 63;
    const int grp = lane >> 4, sub = lane & 15;
    const int nodeBase = blockIdx.x * 16;
    const float scale = 1.0f + *epsp;

    // ---- aggregation: group grp of wave w owns node w*4+grp ----
    const int row  = w * 4 + grp;
    const int node = nodeBase + row;
    const int s = node << 5;
    int d = deg[node]; if (d > BCAP) d = BCAP;
    const int e = s + d;
    const int sub8 = sub * 8;

    h8 acc = (h8)(_Float16)0;
    const h8 zero = (h8)(_Float16)0;
    int j = s;
    for (; j + 1 < e; j += 2) {
        unsigned int p0 = packed[j];
        unsigned int p1 = packed[j + 1];
        h8 g0 = *(const h8*)(xh + ((p0 & 0xffffu) << 7) + sub8);
        h8 g1 = *(const h8*)(xh + ((p1 & 0xffffu) << 7) + sub8);
        h8 q0 = *(const h8*)(projL + (p0 >> 16) * TSTR + sub8);
        h8 q1 = *(const h8*)(projL + (p1 >> 16) * TSTR + sub8);
        acc += __builtin_elementwise_max(g0 + q0, zero);
        acc += __builtin_elementwise_max(g1 + q1, zero);
    }
    if (j < e) {
        unsigned int p0 = packed[j];
        h8 g0 = *(const h8*)(xh + ((p0 & 0xffffu) << 7) + sub8);
        h8 q0 = *(const h8*)(projL + (p0 >> 16) * TSTR + sub8);
        acc += __builtin_elementwise_max(g0 + q0, zero);
    }

    // self term (fp32) + fp16 pack -> Tz
    {
        h8 go = *(const h8*)(xh + ((unsigned)node << 7) + sub8);
        h8 z;
#pragma unroll
        for (int k = 0; k < 8; ++k)
            z[k] = (_Float16)(scale * (float)go[k] + (float)acc[k]);
        *(h8*)(Tz + row * TSTR + sub8) = z;
    }
    __syncthreads();

    // ---- MFMA MLP: wave w owns col-chunks {w, w+4} of each GEMM ----
    const int m = lane & 15, quad = lane >> 4;

    h8 a[4];
#pragma unroll
    for (int kc = 0; kc < 4; ++kc)
        a[kc] = *(const h8*)(Tz + m * TSTR + kc * 32 + quad * 8);

    const h8* w1f = (const h8*)w1p;
#pragma unroll
    for (int cc = 0; cc < 2; ++cc) {
        const int c = w + cc * 4;
        f32x4 acc2 = {0.f, 0.f, 0.f, 0.f};
#pragma unroll
        for (int kc = 0; kc < 4; ++kc)
            acc2 = __builtin_amdgcn_mfma_f32_16x16x32_f16(
                      a[kc], w1f[(c * 4 + kc) * 64 + lane], acc2, 0, 0, 0);
        const int col = c * 16 + m;
        const float bias = b1[col];
#pragma unroll
        for (int r = 0; r < 4; ++r)
            Th[(quad * 4 + r) * TSTR + col] = (_Float16)fmaxf(acc2[r] + bias, 0.0f);
    }
    __syncthreads();

    h8 ha[4];
#pragma unroll
    for (int kc = 0; kc < 4; ++kc)
        ha[kc] = *(const h8*)(Th + m * TSTR + kc * 32 + quad * 8);

    const h8* w2f = (const h8*)w2p;
#pragma unroll
    for (int cc = 0; cc < 2; ++cc) {
        const int c = w + cc * 4;
        f32x4 acc2 = {0.f, 0.f, 0.f, 0.f};
#pragma unroll
        for (int kc = 0; kc < 4; ++kc)
            acc2 = __builtin_amdgcn_mfma_f32_16x16x32_f16(
                      ha[kc], w2f[(c * 4 + kc) * 64 + lane], acc2, 0, 0, 0);
        const int col = c * 16 + m;
        const float bias = b2[col];
#pragma unroll
        for (int r = 0; r < 4; ++r)
            out[(size_t)(nodeBase + quad * 4 + r) * H + col] = acc2[r] + bias;
    }
}

// ---------------------------------------------------------------------------
extern "C" void kernel_launch(void* const* d_in, const int* in_sizes, int n_in,
                              void* d_out, int out_size, void* d_ws, size_t ws_size,
                              hipStream_t stream) {
    const float* x          = (const float*)d_in[0];
    const int*   edge_index = (const int*)  d_in[1];
    const int*   edge_attr  = (const int*)  d_in[2];
    const float* emb        = (const float*)d_in[3];
    const float* We         = (const float*)d_in[4];
    const float* be         = (const float*)d_in[5];
    const float* W1         = (const float*)d_in[6];
    const float* b1         = (const float*)d_in[7];
    const float* W2         = (const float*)d_in[8];
    const float* b2         = (const float*)d_in[9];
    const float* eps        = (const float*)d_in[10];
    float* out = (float*)d_out;

    char* ws = (char*)d_ws;
    size_t off = 0;
    _Float16* projh = (_Float16*)(ws + off); off += (size_t)NTYPES * H * 2;                 // 4 KB
    int* cursor     = (int*)(ws + off);      off += (size_t)NNODES * 4;                     // 200 KB
    unsigned int* packed = (unsigned int*)(ws + off); off += (size_t)NNODES * BCAP * 4;     // 6.4 MB
    _Float16* xh    = (_Float16*)(ws + off); off += (size_t)NNODES * H * 2;                 // 12.8 MB
    _Float16* w1p   = (_Float16*)(ws + off); off += 2048 * 8 * 2;                           // 32 KB
    _Float16* w2p   = (_Float16*)(ws + off); off += 2048 * 8 * 2;                           // 32 KB

    hipMemsetAsync(cursor, 0, (size_t)NNODES * sizeof(int), stream);

    prep_kernel<<<PREP_BLOCKS, 256, 0, stream>>>(
        x, xh, edge_index, edge_attr, cursor, packed,
        emb, We, be, projh, W1, W2, w1p, w2p);

    gine_fused_kernel<<<NNODES / 16, 256, 0, stream>>>(
        xh, cursor, packed, projh, eps, w1p, w2p, b1, b2, out);
}

// Round 10
// 169.630 us; speedup vs baseline: 1.0459x; 1.0198x over previous
//
#include <hip/hip_runtime.h>

#define H       128
#define NNODES  50000
#define NEDGES  640000
#define NTYPES  16
#define EDIM    8
#define BCAP    32        // fixed bucket capacity (lambda=12.8, P(deg>=33)~5e-22 over 50k)
#define TSTR    136       // LDS row stride in halves (16B-aligned, 4-bank shift/row)

// prep_kernel block partition: bucket | xh | proj | pack
#define BKT_BLOCKS  2500                  // 640000 / 256
#define XH_BLOCKS   3125                  // 6.4M elems / 8 / 256
#define PROJ_BLOCKS 8
#define PACK_BLOCKS 16
#define PREP_BLOCKS (BKT_BLOCKS + XH_BLOCKS + PROJ_BLOCKS + PACK_BLOCKS)

typedef _Float16 h8 __attribute__((ext_vector_type(8)));
typedef float    f32x4 __attribute__((ext_vector_type(4)));

// ---------------------------------------------------------------------------
// fused prep; all four parts independent. cursor must be zeroed beforehand.
// ---------------------------------------------------------------------------
__global__ __launch_bounds__(256) void prep_kernel(
        const float* __restrict__ x, _Float16* __restrict__ xh,
        const int* __restrict__ edge_index, const int* __restrict__ edge_attr,
        int* __restrict__ cursor, unsigned int* __restrict__ packed,
        const float* __restrict__ emb, const float* __restrict__ We,
        const float* __restrict__ be, _Float16* __restrict__ projh,
        const float* __restrict__ W1, const float* __restrict__ W2,
        _Float16* __restrict__ w1p, _Float16* __restrict__ w2p) {
    const int b = blockIdx.x;
    const int t = threadIdx.x;

    if (b < BKT_BLOCKS) {
        // bucket: one edge per thread
        int e = b * 256 + t;                 // 2500*256 == 640000 exactly
        int src = edge_index[e];
        int dst = edge_index[NEDGES + e];
        int a0 = edge_attr[e * 3 + 0];
        int a1 = edge_attr[e * 3 + 1];
        int a2 = edge_attr[e * 3 + 2];
        unsigned int h = (unsigned int)(a0 + 3 * a1 + 7 * a2) & (NTYPES - 1);
        int pos = atomicAdd(&cursor[dst], 1);
        if (pos < BCAP)
            packed[((unsigned)dst << 5) + pos] = (unsigned int)src | (h << 16);
    } else if (b < BKT_BLOCKS + XH_BLOCKS) {
        // x (fp32) -> xh (fp16), 8 elems/thread
        int i = ((b - BKT_BLOCKS) * 256 + t) * 8;
        float4 a = *(const float4*)(x + i);
        float4 c = *(const float4*)(x + i + 4);
        h8 o;
        o[0] = (_Float16)a.x; o[1] = (_Float16)a.y;
        o[2] = (_Float16)a.z; o[3] = (_Float16)a.w;
        o[4] = (_Float16)c.x; o[5] = (_Float16)c.y;
        o[6] = (_Float16)c.z; o[7] = (_Float16)c.w;
        *(h8*)(xh + i) = o;
    } else if (b < BKT_BLOCKS + XH_BLOCKS + PROJ_BLOCKS) {
        // projh[t][f] = fp16(be[f] + sum_d emb[t][d]*We[d][f])
        int id = (b - BKT_BLOCKS - XH_BLOCKS) * 256 + t;   // 0..2047
        int ty = id >> 7;
        int f  = id & (H - 1);
        float acc = be[f];
#pragma unroll
        for (int d = 0; d < EDIM; ++d)
            acc += emb[ty * EDIM + d] * We[d * H + f];
        projh[id] = (_Float16)acc;
    } else {
        // pack W1/W2 into MFMA B-fragment order (fp16); layout verified R4
        int id = (b - BKT_BLOCKS - XH_BLOCKS - PROJ_BLOCKS) * 256 + t; // 0..4095
        const float* W = (id < 2048) ? W1 : W2;
        _Float16* P = (id < 2048) ? w1p : w2p;
        int q = id & 2047;
        int lane = q & 63;
        int kc = (q >> 6) & 3;
        int c  = q >> 8;
        int n = c * 16 + (lane & 15);
        int kbase = kc * 32 + (lane >> 4) * 8;
#pragma unroll
        for (int j = 0; j < 8; ++j)
            P[q * 8 + j] = (_Float16)W[(kbase + j) * H + n];
    }
}

// ---------------------------------------------------------------------------
// fused: block = 16 nodes = one MFMA tile, 4 waves; 16-lane group per node.
// Bucket is staged to LDS (one dwordx2 per lane) behind the projL barrier,
// so the gather loop has no global->global pointer chase; 4-deep unroll
// keeps 16 xh loads in flight per wave.
// ---------------------------------------------------------------------------
__global__ __launch_bounds__(256) void gine_fused_kernel(
        const _Float16* __restrict__ xh,
        const int* __restrict__ deg,
        const unsigned int* __restrict__ packed,
        const _Float16* __restrict__ projh,
        const float* __restrict__ epsp,
        const _Float16* __restrict__ w1p,
        const _Float16* __restrict__ w2p,
        const float* __restrict__ b1,
        const float* __restrict__ b2,
        float* __restrict__ out) {
    __shared__ _Float16 projL[NTYPES * TSTR];    // 4.25 KB
    __shared__ _Float16 Tz[16 * TSTR];           // 4.25 KB
    __shared__ _Float16 Th[16 * TSTR];           // 4.25 KB
    __shared__ unsigned int ebuf[16][BCAP];      // 2 KB
    const int t = threadIdx.x;
    const int w = t >> 6, lane = t & 63;
    const int grp = lane >> 4, sub = lane & 15;
    const int nodeBase = blockIdx.x * 16;
    const int row  = w * 4 + grp;
    const int node = nodeBase + row;

    // stage projh [16][128] -> projL stride 136 (one 16B chunk per thread)
    {
        int r = t >> 4, cc = (t & 15) * 8;
        *(h8*)(projL + r * TSTR + cc) = *(const h8*)(projh + r * H + cc);
    }
    // stage this group's full bucket: 16 lanes x dwordx2 = 32 entries
    {
        uint2 pp = *(const uint2*)(packed + ((unsigned)node << 5) + sub * 2);
        *(uint2*)(&ebuf[row][sub * 2]) = pp;
    }
    __syncthreads();

    const float scale = 1.0f + *epsp;
    int d = deg[node]; if (d > BCAP) d = BCAP;
    const int sub8 = sub * 8;

    h8 acc = (h8)(_Float16)0;
    const h8 zero = (h8)(_Float16)0;
    int j = 0;
    for (; j + 3 < d; j += 4) {
        uint4 p = *(const uint4*)(&ebuf[row][j]);   // broadcast b128
        h8 g0 = *(const h8*)(xh + ((p.x & 0xffffu) << 7) + sub8);
        h8 g1 = *(const h8*)(xh + ((p.y & 0xffffu) << 7) + sub8);
        h8 g2 = *(const h8*)(xh + ((p.z & 0xffffu) << 7) + sub8);
        h8 g3 = *(const h8*)(xh + ((p.w & 0xffffu) << 7) + sub8);
        h8 q0 = *(const h8*)(projL + (p.x >> 16) * TSTR + sub8);
        h8 q1 = *(const h8*)(projL + (p.y >> 16) * TSTR + sub8);
        h8 q2 = *(const h8*)(projL + (p.z >> 16) * TSTR + sub8);
        h8 q3 = *(const h8*)(projL + (p.w >> 16) * TSTR + sub8);
        acc += __builtin_elementwise_max(g0 + q0, zero);
        acc += __builtin_elementwise_max(g1 + q1, zero);
        acc += __builtin_elementwise_max(g2 + q2, zero);
        acc += __builtin_elementwise_max(g3 + q3, zero);
    }
    for (; j < d; ++j) {
        unsigned int p0 = ebuf[row][j];
        h8 g0 = *(const h8*)(xh + ((p0 & 0xffffu) << 7) + sub8);
        h8 q0 = *(const h8*)(projL + (p0 >> 16) * TSTR + sub8);
        acc += __builtin_elementwise_max(g0 + q0, zero);
    }

    // self term (fp32) + fp16 pack -> Tz
    {
        h8 go = *(const h8*)(xh + ((unsigned)node << 7) + sub8);
        h8 z;
#pragma unroll
        for (int k = 0; k < 8; ++k)
            z[k] = (_Float16)(scale * (float)go[k] + (float)acc[k]);
        *(h8*)(Tz + row * TSTR + sub8) = z;
    }
    __syncthreads();

    // ---- MFMA MLP: wave w owns col-chunks {w, w+4} of each GEMM ----
    const int m = lane & 15, quad = lane >> 4;

    h8 a[4];
#pragma unroll
    for (int kc = 0; kc < 4; ++kc)
        a[kc] = *(const h8*)(Tz + m * TSTR + kc * 32 + quad * 8);

    const h8* w1f = (const h8*)w1p;
#pragma unroll
    for (int cc = 0; cc < 2; ++cc) {
        const int c = w + cc * 4;
        f32x4 acc2 = {0.f, 0.f, 0.f, 0.f};
#pragma unroll
        for (int kc = 0; kc < 4; ++kc)
            acc2 = __builtin_amdgcn_mfma_f32_16x16x32_f16(
                      a[kc], w1f[(c * 4 + kc) * 64 + lane], acc2, 0, 0, 0);
        const int col = c * 16 + m;
        const float bias = b1[col];
#pragma unroll
        for (int r = 0; r < 4; ++r)
            Th[(quad * 4 + r) * TSTR + col] = (_Float16)fmaxf(acc2[r] + bias, 0.0f);
    }
    __syncthreads();

    h8 ha[4];
#pragma unroll
    for (int kc = 0; kc < 4; ++kc)
        ha[kc] = *(const h8*)(Th + m * TSTR + kc * 32 + quad * 8);

    const h8* w2f = (const h8*)w2p;
#pragma unroll
    for (int cc = 0; cc < 2; ++cc) {
        const int c = w + cc * 4;
        f32x4 acc2 = {0.f, 0.f, 0.f, 0.f};
#pragma unroll
        for (int kc = 0; kc < 4; ++kc)
            acc2 = __builtin_amdgcn_mfma_f32_16x16x32_f16(
                      ha[kc], w2f[(c * 4 + kc) * 64 + lane], acc2, 0, 0, 0);
        const int col = c * 16 + m;
        const float bias = b2[col];
#pragma unroll
        for (int r = 0; r < 4; ++r)
            out[(size_t)(nodeBase + quad * 4 + r) * H + col] = acc2[r] + bias;
    }
}

// ---------------------------------------------------------------------------
extern "C" void kernel_launch(void* const* d_in, const int* in_sizes, int n_in,
                              void* d_out, int out_size, void* d_ws, size_t ws_size,
                              hipStream_t stream) {
    const float* x          = (const float*)d_in[0];
    const int*   edge_index = (const int*)  d_in[1];
    const int*   edge_attr  = (const int*)  d_in[2];
    const float* emb        = (const float*)d_in[3];
    const float* We         = (const float*)d_in[4];
    const float* be         = (const float*)d_in[5];
    const float* W1         = (const float*)d_in[6];
    const float* b1         = (const float*)d_in[7];
    const float* W2         = (const float*)d_in[8];
    const float* b2         = (const float*)d_in[9];
    const float* eps        = (const float*)d_in[10];
    float* out = (float*)d_out;

    char* ws = (char*)d_ws;
    size_t off = 0;
    _Float16* projh = (_Float16*)(ws + off); off += (size_t)NTYPES * H * 2;                 // 4 KB
    int* cursor     = (int*)(ws + off);      off += (size_t)NNODES * 4;                     // 200 KB
    unsigned int* packed = (unsigned int*)(ws + off); off += (size_t)NNODES * BCAP * 4;     // 6.4 MB
    _Float16* xh    = (_Float16*)(ws + off); off += (size_t)NNODES * H * 2;                 // 12.8 MB
    _Float16* w1p   = (_Float16*)(ws + off); off += 2048 * 8 * 2;                           // 32 KB
    _Float16* w2p   = (_Float16*)(ws + off); off += 2048 * 8 * 2;                           // 32 KB

    hipMemsetAsync(cursor, 0, (size_t)NNODES * sizeof(int), stream);

    prep_kernel<<<PREP_BLOCKS, 256, 0, stream>>>(
        x, xh, edge_index, edge_attr, cursor, packed,
        emb, We, be, projh, W1, W2, w1p, w2p);

    gine_fused_kernel<<<NNODES / 16, 256, 0, stream>>>(
        xh, cursor, packed, projh, eps, w1p, w2p, b1, b2, out);
}

// Round 11
// 169.313 us; speedup vs baseline: 1.0478x; 1.0019x over previous
//
#include <hip/hip_runtime.h>

#define H       128
#define NNODES  50000
#define NEDGES  640000
#define NTYPES  16
#define EDIM    8
#define BCAP    32        // fixed bucket capacity (lambda=12.8, P(deg>=33)~5e-22 over 50k)
#define TSTR    136       // LDS row stride in halves (16B-aligned, 4-bank shift/row)

// prep_kernel block partition: bucket | xh | proj | pack
#define BKT_BLOCKS  2500                  // 640000 / 256
#define XH_BLOCKS   3125                  // 6.4M elems / 8 / 256
#define PROJ_BLOCKS 8
#define PACK_BLOCKS 16
#define PREP_BLOCKS (BKT_BLOCKS + XH_BLOCKS + PROJ_BLOCKS + PACK_BLOCKS)

typedef _Float16 h8 __attribute__((ext_vector_type(8)));
typedef float    f32x4 __attribute__((ext_vector_type(4)));

// ---------------------------------------------------------------------------
// fused prep; all four parts independent. cursor must be zeroed beforehand.
// ---------------------------------------------------------------------------
__global__ __launch_bounds__(256) void prep_kernel(
        const float* __restrict__ x, _Float16* __restrict__ xh,
        const int* __restrict__ edge_index, const int* __restrict__ edge_attr,
        int* __restrict__ cursor, unsigned int* __restrict__ packed,
        const float* __restrict__ emb, const float* __restrict__ We,
        const float* __restrict__ be, _Float16* __restrict__ projh,
        const float* __restrict__ W1, const float* __restrict__ W2,
        _Float16* __restrict__ w1p, _Float16* __restrict__ w2p) {
    const int b = blockIdx.x;
    const int t = threadIdx.x;

    if (b < BKT_BLOCKS) {
        // bucket: one edge per thread
        int e = b * 256 + t;                 // 2500*256 == 640000 exactly
        int src = edge_index[e];
        int dst = edge_index[NEDGES + e];
        int a0 = edge_attr[e * 3 + 0];
        int a1 = edge_attr[e * 3 + 1];
        int a2 = edge_attr[e * 3 + 2];
        unsigned int h = (unsigned int)(a0 + 3 * a1 + 7 * a2) & (NTYPES - 1);
        int pos = atomicAdd(&cursor[dst], 1);
        if (pos < BCAP)
            packed[((unsigned)dst << 5) + pos] = (unsigned int)src | (h << 16);
    } else if (b < BKT_BLOCKS + XH_BLOCKS) {
        // x (fp32) -> xh (fp16), 8 elems/thread
        int i = ((b - BKT_BLOCKS) * 256 + t) * 8;
        float4 a = *(const float4*)(x + i);
        float4 c = *(const float4*)(x + i + 4);
        h8 o;
        o[0] = (_Float16)a.x; o[1] = (_Float16)a.y;
        o[2] = (_Float16)a.z; o[3] = (_Float16)a.w;
        o[4] = (_Float16)c.x; o[5] = (_Float16)c.y;
        o[6] = (_Float16)c.z; o[7] = (_Float16)c.w;
        *(h8*)(xh + i) = o;
    } else if (b < BKT_BLOCKS + XH_BLOCKS + PROJ_BLOCKS) {
        // projh[t][f] = fp16(be[f] + sum_d emb[t][d]*We[d][f])
        int id = (b - BKT_BLOCKS - XH_BLOCKS) * 256 + t;   // 0..2047
        int ty = id >> 7;
        int f  = id & (H - 1);
        float acc = be[f];
#pragma unroll
        for (int d = 0; d < EDIM; ++d)
            acc += emb[ty * EDIM + d] * We[d * H + f];
        projh[id] = (_Float16)acc;
    } else {
        // pack W1/W2 into MFMA B-fragment order (fp16); layout verified R4
        int id = (b - BKT_BLOCKS - XH_BLOCKS - PROJ_BLOCKS) * 256 + t; // 0..4095
        const float* W = (id < 2048) ? W1 : W2;
        _Float16* P = (id < 2048) ? w1p : w2p;
        int q = id & 2047;
        int lane = q & 63;
        int kc = (q >> 6) & 3;
        int c  = q >> 8;
        int n = c * 16 + (lane & 15);
        int kbase = kc * 32 + (lane >> 4) * 8;
#pragma unroll
        for (int j = 0; j < 8; ++j)
            P[q * 8 + j] = (_Float16)W[(kbase + j) * H + n];
    }
}

// ---------------------------------------------------------------------------
// fused: block = 16 nodes = one MFMA tile, 4 waves; 16-lane group per node.
// Bucket staged to LDS behind the projL barrier. Gather loop is 8-deep:
// all 8 xh dwordx4 loads issue before any consumption (8 outstanding/wave),
// projL reads interleave into the consume chain. launch_bounds(256,8) pins
// VGPR <= 64 so 8 waves/SIMD are retained.
// ---------------------------------------------------------------------------
__global__ __launch_bounds__(256, 8) void gine_fused_kernel(
        const _Float16* __restrict__ xh,
        const int* __restrict__ deg,
        const unsigned int* __restrict__ packed,
        const _Float16* __restrict__ projh,
        const float* __restrict__ epsp,
        const _Float16* __restrict__ w1p,
        const _Float16* __restrict__ w2p,
        const float* __restrict__ b1,
        const float* __restrict__ b2,
        float* __restrict__ out) {
    __shared__ _Float16 projL[NTYPES * TSTR];    // 4.25 KB
    __shared__ _Float16 Tz[16 * TSTR];           // 4.25 KB
    __shared__ _Float16 Th[16 * TSTR];           // 4.25 KB
    __shared__ unsigned int ebuf[16][BCAP];      // 2 KB
    const int t = threadIdx.x;
    const int w = t >> 6, lane = t & 63;
    const int grp = lane >> 4, sub = lane & 15;
    const int nodeBase = blockIdx.x * 16;
    const int row  = w * 4 + grp;
    const int node = nodeBase + row;

    // stage projh [16][128] -> projL stride 136 (one 16B chunk per thread)
    {
        int r = t >> 4, cc = (t & 15) * 8;
        *(h8*)(projL + r * TSTR + cc) = *(const h8*)(projh + r * H + cc);
    }
    // stage this group's full bucket: 16 lanes x dwordx2 = 32 entries
    {
        uint2 pp = *(const uint2*)(packed + ((unsigned)node << 5) + sub * 2);
        *(uint2*)(&ebuf[row][sub * 2]) = pp;
    }
    __syncthreads();

    const float scale = 1.0f + *epsp;
    int d = deg[node]; if (d > BCAP) d = BCAP;
    const int sub8 = sub * 8;

    // self-term load in flight across the whole gather
    h8 go = *(const h8*)(xh + ((unsigned)node << 7) + sub8);

    h8 acc = (h8)(_Float16)0;
    const h8 zero = (h8)(_Float16)0;
    int j = 0;
    for (; j + 7 < d; j += 8) {
        uint4 pa = *(const uint4*)(&ebuf[row][j]);
        uint4 pb = *(const uint4*)(&ebuf[row][j + 4]);
        h8 g0 = *(const h8*)(xh + ((pa.x & 0xffffu) << 7) + sub8);
        h8 g1 = *(const h8*)(xh + ((pa.y & 0xffffu) << 7) + sub8);
        h8 g2 = *(const h8*)(xh + ((pa.z & 0xffffu) << 7) + sub8);
        h8 g3 = *(const h8*)(xh + ((pa.w & 0xffffu) << 7) + sub8);
        h8 g4 = *(const h8*)(xh + ((pb.x & 0xffffu) << 7) + sub8);
        h8 g5 = *(const h8*)(xh + ((pb.y & 0xffffu) << 7) + sub8);
        h8 g6 = *(const h8*)(xh + ((pb.z & 0xffffu) << 7) + sub8);
        h8 g7 = *(const h8*)(xh + ((pb.w & 0xffffu) << 7) + sub8);
        acc += __builtin_elementwise_max(g0 + *(const h8*)(projL + (pa.x >> 16) * TSTR + sub8), zero);
        acc += __builtin_elementwise_max(g1 + *(const h8*)(projL + (pa.y >> 16) * TSTR + sub8), zero);
        acc += __builtin_elementwise_max(g2 + *(const h8*)(projL + (pa.z >> 16) * TSTR + sub8), zero);
        acc += __builtin_elementwise_max(g3 + *(const h8*)(projL + (pa.w >> 16) * TSTR + sub8), zero);
        acc += __builtin_elementwise_max(g4 + *(const h8*)(projL + (pb.x >> 16) * TSTR + sub8), zero);
        acc += __builtin_elementwise_max(g5 + *(const h8*)(projL + (pb.y >> 16) * TSTR + sub8), zero);
        acc += __builtin_elementwise_max(g6 + *(const h8*)(projL + (pb.z >> 16) * TSTR + sub8), zero);
        acc += __builtin_elementwise_max(g7 + *(const h8*)(projL + (pb.w >> 16) * TSTR + sub8), zero);
    }
    for (; j + 3 < d; j += 4) {
        uint4 p = *(const uint4*)(&ebuf[row][j]);
        h8 g0 = *(const h8*)(xh + ((p.x & 0xffffu) << 7) + sub8);
        h8 g1 = *(const h8*)(xh + ((p.y & 0xffffu) << 7) + sub8);
        h8 g2 = *(const h8*)(xh + ((p.z & 0xffffu) << 7) + sub8);
        h8 g3 = *(const h8*)(xh + ((p.w & 0xffffu) << 7) + sub8);
        acc += __builtin_elementwise_max(g0 + *(const h8*)(projL + (p.x >> 16) * TSTR + sub8), zero);
        acc += __builtin_elementwise_max(g1 + *(const h8*)(projL + (p.y >> 16) * TSTR + sub8), zero);
        acc += __builtin_elementwise_max(g2 + *(const h8*)(projL + (p.z >> 16) * TSTR + sub8), zero);
        acc += __builtin_elementwise_max(g3 + *(const h8*)(projL + (p.w >> 16) * TSTR + sub8), zero);
    }
    for (; j < d; ++j) {
        unsigned int p0 = ebuf[row][j];
        h8 g0 = *(const h8*)(xh + ((p0 & 0xffffu) << 7) + sub8);
        h8 q0 = *(const h8*)(projL + (p0 >> 16) * TSTR + sub8);
        acc += __builtin_elementwise_max(g0 + q0, zero);
    }

    // self term (fp32) + fp16 pack -> Tz
    {
        h8 z;
#pragma unroll
        for (int k = 0; k < 8; ++k)
            z[k] = (_Float16)(scale * (float)go[k] + (float)acc[k]);
        *(h8*)(Tz + row * TSTR + sub8) = z;
    }
    __syncthreads();

    // ---- MFMA MLP: wave w owns col-chunks {w, w+4} of each GEMM ----
    const int m = lane & 15, quad = lane >> 4;

    h8 a[4];
#pragma unroll
    for (int kc = 0; kc < 4; ++kc)
        a[kc] = *(const h8*)(Tz + m * TSTR + kc * 32 + quad * 8);

    const h8* w1f = (const h8*)w1p;
#pragma unroll
    for (int cc = 0; cc < 2; ++cc) {
        const int c = w + cc * 4;
        f32x4 acc2 = {0.f, 0.f, 0.f, 0.f};
#pragma unroll
        for (int kc = 0; kc < 4; ++kc)
            acc2 = __builtin_amdgcn_mfma_f32_16x16x32_f16(
                      a[kc], w1f[(c * 4 + kc) * 64 + lane], acc2, 0, 0, 0);
        const int col = c * 16 + m;
        const float bias = b1[col];
#pragma unroll
        for (int r = 0; r < 4; ++r)
            Th[(quad * 4 + r) * TSTR + col] = (_Float16)fmaxf(acc2[r] + bias, 0.0f);
    }
    __syncthreads();

    h8 ha[4];
#pragma unroll
    for (int kc = 0; kc < 4; ++kc)
        ha[kc] = *(const h8*)(Th + m * TSTR + kc * 32 + quad * 8);

    const h8* w2f = (const h8*)w2p;
#pragma unroll
    for (int cc = 0; cc < 2; ++cc) {
        const int c = w + cc * 4;
        f32x4 acc2 = {0.f, 0.f, 0.f, 0.f};
#pragma unroll
        for (int kc = 0; kc < 4; ++kc)
            acc2 = __builtin_amdgcn_mfma_f32_16x16x32_f16(
                      ha[kc], w2f[(c * 4 + kc) * 64 + lane], acc2, 0, 0, 0);
        const int col = c * 16 + m;
        const float bias = b2[col];
#pragma unroll
        for (int r = 0; r < 4; ++r)
            __builtin_nontemporal_store(acc2[r] + bias,
                out + (size_t)(nodeBase + quad * 4 + r) * H + col);
    }
}

// ---------------------------------------------------------------------------
extern "C" void kernel_launch(void* const* d_in, const int* in_sizes, int n_in,
                              void* d_out, int out_size, void* d_ws, size_t ws_size,
                              hipStream_t stream) {
    const float* x          = (const float*)d_in[0];
    const int*   edge_index = (const int*)  d_in[1];
    const int*   edge_attr  = (const int*)  d_in[2];
    const float* emb        = (const float*)d_in[3];
    const float* We         = (const float*)d_in[4];
    const float* be         = (const float*)d_in[5];
    const float* W1         = (const float*)d_in[6];
    const float* b1         = (const float*)d_in[7];
    const float* W2         = (const float*)d_in[8];
    const float* b2         = (const float*)d_in[9];
    const float* eps        = (const float*)d_in[10];
    float* out = (float*)d_out;

    char* ws = (char*)d_ws;
    size_t off = 0;
    _Float16* projh = (_Float16*)(ws + off); off += (size_t)NTYPES * H * 2;                 // 4 KB
    int* cursor     = (int*)(ws + off);      off += (size_t)NNODES * 4;                     // 200 KB
    unsigned int* packed = (unsigned int*)(ws + off); off += (size_t)NNODES * BCAP * 4;     // 6.4 MB
    _Float16* xh    = (_Float16*)(ws + off); off += (size_t)NNODES * H * 2;                 // 12.8 MB
    _Float16* w1p   = (_Float16*)(ws + off); off += 2048 * 8 * 2;                           // 32 KB
    _Float16* w2p   = (_Float16*)(ws + off); off += 2048 * 8 * 2;                           // 32 KB

    hipMemsetAsync(cursor, 0, (size_t)NNODES * sizeof(int), stream);

    prep_kernel<<<PREP_BLOCKS, 256, 0, stream>>>(
        x, xh, edge_index, edge_attr, cursor, packed,
        emb, We, be, projh, W1, W2, w1p, w2p);

    gine_fused_kernel<<<NNODES / 16, 256, 0, stream>>>(
        xh, cursor, packed, projh, eps, w1p, w2p, b1, b2, out);
}